// Round 1
// baseline (96.700 us; speedup 1.0000x reference)
//
#include <hip/hip_runtime.h>

// 4-level lifting wavelet, fully fused into one kernel.
// B=512 rows, N=65536. Each block handles one (row, 4096-element chunk),
// with a 256-element circular left halo (all lifting convs are left-looking:
// roll(x,k), k=0..2). Garbage-propagation analysis: halo >= 224 suffices.
#define BS    256
#define CHUNK 4096
#define HALO  256
#define TOT   (CHUNK + HALO)   // 4352
#define NN    65536

__device__ __forceinline__ void conv_sub(float* O, const float* E, int len,
                                         float c0, float c1, float c2, int tid) {
  // O[n] -= c0*E[n] + c1*E[n-1] + c2*E[n-2]  (clamped; left edge is halo garbage)
  for (int n = tid; n < len; n += BS) {
    int n1 = n > 0 ? n - 1 : 0;
    int n2 = n > 1 ? n - 2 : 0;
    O[n] -= c0 * E[n] + c1 * E[n1] + c2 * E[n2];
  }
}

__device__ __forceinline__ void conv_add(float* E, const float* O, int len,
                                         float c0, float c1, float c2, int tid) {
  for (int n = tid; n < len; n += BS) {
    int n1 = n > 0 ? n - 1 : 0;
    int n2 = n > 1 ? n - 2 : 0;
    E[n] += c0 * O[n] + c1 * O[n1] + c2 * O[n2];
  }
}

// Two lifting pairs: rows (2j) and (2j+1) of P/U, passed as 6 consecutive floats.
__device__ __forceinline__ void lift(float* E, float* O, int len,
                                     const float* P, const float* U, int tid) {
  conv_sub(O, E, len, P[0], P[1], P[2], tid); __syncthreads();
  conv_add(E, O, len, U[0], U[1], U[2], tid); __syncthreads();
  conv_sub(O, E, len, P[3], P[4], P[5], tid); __syncthreads();
  conv_add(E, O, len, U[3], U[4], U[5], tid); __syncthreads();
}

__device__ __forceinline__ void deint(const float* src, float* E, float* O,
                                      int halflen, int tid) {
  const float2* s2 = (const float2*)src;
  for (int m = tid; m < halflen; m += BS) {
    float2 v = s2[m];
    E[m] = v.x;
    O[m] = v.y;
  }
}

__device__ __forceinline__ void store4(float* dst, const float* src, int n4, int tid) {
  const float4* s = (const float4*)src;
  float4* d = (float4*)dst;
  for (int i = tid; i < n4; i += BS) d[i] = s[i];
}

__global__ __launch_bounds__(BS)
void wavelet_fused_kernel(const float* __restrict__ x,
                          const float* __restrict__ Pc,
                          const float* __restrict__ Uc,
                          float* __restrict__ out) {
  __shared__ __align__(16) float lds[8704];   // 34.8 KB
  float* A = lds;          // 4352 floats
  float* E = lds + 4352;   // 2176 floats
  float* D = lds + 6528;   // 2176 floats

  const int tid = threadIdx.x;
  const int cx  = blockIdx.x;        // chunk 0..15
  const int row = blockIdx.y;        // row 0..511
  const int S   = cx * CHUNK;

  // ---- load chunk + circular left halo (float4, pow2 mask wrap) ----
  const float4* x4 = (const float4*)(x + (size_t)row * NN);
  const int base4 = ((S - HALO) & (NN - 1)) >> 2;
  float4* A4 = (float4*)A;
  for (int i = tid; i < TOT / 4; i += BS)
    A4[i] = x4[(base4 + i) & (NN / 4 - 1)];
  __syncthreads();

  // ---- level 0: A(4352) -> E,D (2176 each) ----
  deint(A, E, D, 2176, tid);
  __syncthreads();
  lift(E, D, 2176, Pc, Uc, tid);
  // z0: 2048 floats, valid-from 8 <= 128
  store4(out + (size_t)row * 32768 + (S >> 1), E + 128, 512, tid);

  // ---- level 1: D(2176) -> A[0..1088), A[1088..2176) ----
  deint(D, A, A + 1088, 1088, tid);
  __syncthreads();
  lift(A, A + 1088, 1088, Pc + 6, Uc + 6, tid);
  store4(out + 16777216 + (size_t)row * 16384 + (S >> 2), A + 64, 256, tid);

  // ---- level 2: A+1088 (1088) -> E[0..544), E[544..1088) ----
  deint(A + 1088, E, E + 544, 544, tid);
  __syncthreads();
  lift(E, E + 544, 544, Pc + 12, Uc + 12, tid);
  store4(out + 25165824 + (size_t)row * 8192 + (S >> 3), E + 32, 128, tid);

  // ---- level 3: E+544 (544) -> D[0..272), D[272..544) ----
  deint(E + 544, D, D + 272, 272, tid);
  __syncthreads();
  lift(D, D + 272, 272, Pc + 18, Uc + 18, tid);
  store4(out + 29360128 + (size_t)row * 4096 + (S >> 4), D + 16, 64, tid);   // z3
  store4(out + 31457280 + (size_t)row * 4096 + (S >> 4), D + 288, 64, tid);  // z4
}

extern "C" void kernel_launch(void* const* d_in, const int* in_sizes, int n_in,
                              void* d_out, int out_size, void* d_ws, size_t ws_size,
                              hipStream_t stream) {
  const float* x  = (const float*)d_in[0];
  const float* Pc = (const float*)d_in[1];
  const float* Uc = (const float*)d_in[2];
  float* out = (float*)d_out;

  dim3 grid(NN / CHUNK, 512, 1);   // 16 chunks x 512 rows
  dim3 block(BS, 1, 1);
  wavelet_fused_kernel<<<grid, block, 0, stream>>>(x, Pc, Uc, out);
}

// Round 2
// 52.658 us; speedup vs baseline: 1.8364x; 1.8364x over previous
//
#include <hip/hip_runtime.h>

// 4-level lifting wavelet, fully fused, register-lifted.
// B=512 rows, N=65536. Block = (row, 4096-chunk) + 256-elem circular left halo.
// Per level, each thread computes M output pairs in registers with an 8-pair
// recompute halo (dependency depth of the 4 conv passes is 8 pairs), so each
// level is ONE LDS read phase + ONE LDS write phase (2 barriers), and all
// level buffers alias inside a single 4352-float LDS array (17.4 KB -> ~8
// blocks/CU vs 4 before).
#define BS    256
#define CHUNK 4096
#define HALO  256
#define NN    65536

// Per-level lifting: input pairs at lds[inOff + 2p], p in [0,npairs).
// Thread t owns pairs [M*t, M*t+M); reads window [M*t-8, M*t+M) to registers,
// syncs, then computes streaming and writes avg->lds[avgOff+p], det->lds[detOff+p].
// Write regions may alias the input region: all inputs are in registers before
// the internal barrier.
template<int M>
__device__ __forceinline__ void level_lift(float* lds, int inOff, int npairs,
                                           int avgOff, int detOff,
                                           const float* __restrict__ Pc,
                                           const float* __restrict__ Uc,
                                           int tid) {
  const int W = M + 8;
  float in[2 * (M + 8)];
  const int p0 = M * tid - 8;
#pragma unroll
  for (int i = 0; i < W; ++i) {
    int p = p0 + i;
    p = p < 0 ? 0 : (p >= npairs ? npairs - 1 : p);
    float2 v = *(const float2*)&lds[inOff + 2 * p];
    in[2 * i] = v.x;
    in[2 * i + 1] = v.y;
  }
  const float P0 = Pc[0], P1 = Pc[1], P2 = Pc[2], P3 = Pc[3], P4 = Pc[4], P5 = Pc[5];
  const float U0 = Uc[0], U1 = Uc[1], U2 = Uc[2], U3 = Uc[3], U4 = Uc[4], U5 = Uc[5];
  __syncthreads();   // all inputs in regs; writes below may overwrite input region
  float e1 = 0, e2 = 0, d1 = 0, d2 = 0, a1 = 0, a2 = 0, f1 = 0, f2 = 0;
#pragma unroll
  for (int i = 0; i < W; ++i) {
    float e0 = in[2 * i], o0 = in[2 * i + 1];
    float d0 = o0 - (P0 * e0 + P1 * e1 + P2 * e2);
    float a0 = e0 + (U0 * d0 + U1 * d1 + U2 * d2);
    float f0 = d0 - (P3 * a0 + P4 * a1 + P5 * a2);
    float b0 = a0 + (U3 * f0 + U4 * f1 + U5 * f2);
    if (i >= 8) {
      int p = p0 + i;               // = M*tid + (i-8) >= 0
      if (p < npairs) {
        lds[avgOff + p] = b0;
        lds[detOff + p] = f0;
      }
    }
    e2 = e1; e1 = e0; d2 = d1; d1 = d0; a2 = a1; a1 = a0; f2 = f1; f1 = f0;
  }
}

__device__ __forceinline__ void store4(float* dst, const float* src, int n4, int tid) {
  const float4* s = (const float4*)src;
  float4* d = (float4*)dst;
  for (int i = tid; i < n4; i += BS) d[i] = s[i];
}

__global__ __launch_bounds__(BS)
void wavelet_fused_kernel(const float* __restrict__ x,
                          const float* __restrict__ Pc,
                          const float* __restrict__ Uc,
                          float* __restrict__ out) {
  __shared__ __align__(16) float A[CHUNK + HALO];   // 4352 floats = 17.4 KB

  const int tid = threadIdx.x;
  const int cx  = blockIdx.x;   // chunk 0..15
  const int row = blockIdx.y;   // row 0..511
  const int S   = cx * CHUNK;

  // ---- load chunk + circular left halo (real wrapped data) ----
  const float4* x4 = (const float4*)(x + (size_t)row * NN);
  const int base4 = ((S - HALO) & (NN - 1)) >> 2;
  float4* A4 = (float4*)A;
#pragma unroll
  for (int i = tid; i < (CHUNK + HALO) / 4; i += BS)
    A4[i] = x4[(base4 + i) & (NN / 4 - 1)];
  __syncthreads();

  // ---- level 0: pairs in A[0..4352) -> avg A[0..2176), det A[2176..4352) ----
  level_lift<9>(A, 0, 2176, 0, 2176, Pc, Uc, tid);
  __syncthreads();
  // z0: avg pairs 128..2176 (2048 floats), global pair offset S/2
  store4(out + (size_t)row * 32768 + (S >> 1), A + 128, 512, tid);

  // ---- level 1: det0 A[2176..4352) -> avg A[0..1088), det A[1088..2176) ----
  level_lift<5>(A, 2176, 1088, 0, 1088, Pc + 6, Uc + 6, tid);
  __syncthreads();
  store4(out + 16777216 + (size_t)row * 16384 + (S >> 2), A + 64, 256, tid);

  // ---- level 2: det1 A[1088..2176) -> avg A[0..544), det A[544..1088) ----
  level_lift<3>(A, 1088, 544, 0, 544, Pc + 12, Uc + 12, tid);
  __syncthreads();
  store4(out + 25165824 + (size_t)row * 8192 + (S >> 3), A + 32, 128, tid);

  // ---- level 3: det2 A[544..1088) -> avg A[0..272), det A[272..544) ----
  level_lift<2>(A, 544, 272, 0, 272, Pc + 18, Uc + 18, tid);
  __syncthreads();
  store4(out + 29360128 + (size_t)row * 4096 + (S >> 4), A + 16, 64, tid);   // z3
  store4(out + 31457280 + (size_t)row * 4096 + (S >> 4), A + 288, 64, tid);  // z4
}

extern "C" void kernel_launch(void* const* d_in, const int* in_sizes, int n_in,
                              void* d_out, int out_size, void* d_ws, size_t ws_size,
                              hipStream_t stream) {
  const float* x  = (const float*)d_in[0];
  const float* Pc = (const float*)d_in[1];
  const float* Uc = (const float*)d_in[2];
  float* out = (float*)d_out;

  dim3 grid(NN / CHUNK, 512, 1);
  dim3 block(BS, 1, 1);
  wavelet_fused_kernel<<<grid, block, 0, stream>>>(x, Pc, Uc, out);
}